// Round 10
// baseline (1883.512 us; speedup 1.0000x reference)
//
#include <hip/hip_runtime.h>
#include <hip/hip_bf16.h>

#define N_NODES 50000
#define N_EDGES 1200000
#define F_IN 128
#define HID 64
#define N_CLASSES 10
#define N_GRAPHS 256
#define EPSF 1e-5f

#define BSZ 128                     // nodes per bucket
#define NB 391                      // ceil(50000/128)
#define BIN_CHUNK 8192              // edges per k_bin block

__device__ __forceinline__ float bf2f(unsigned short u) {
    return __uint_as_float((unsigned)u << 16);
}
__device__ __forceinline__ unsigned short f2bf(float f) {
    __hip_bfloat16 h = __float2bfloat16(f);  // RNE
    return *reinterpret_cast<unsigned short*>(&h);
}

// ---------------- degree histogram ----------------

__global__ void k_hist(const int* __restrict__ dst, int* __restrict__ cnt) {
    int e = blockIdx.x * blockDim.x + threadIdx.x;
    if (e < N_EDGES) atomicAdd(&cnt[dst[e]], 1);
}

// single-block exclusive scan over N_NODES ints; emits dinv = rsqrt(cnt+1) and
// per-bucket cursor bases bcur[b] = offs[b*BSZ] (consumed by k_bin's run claims).
__global__ __launch_bounds__(1024) void k_scan(const int* __restrict__ cnt,
                                               int* __restrict__ offs,
                                               int* __restrict__ bcur,
                                               float* __restrict__ dinv) {
    __shared__ int wsum[16];
    __shared__ int s_carry;
    int tid = threadIdx.x;
    int lane = tid & 63, wid = tid >> 6;
    if (tid == 0) s_carry = 0;
    __syncthreads();
    for (int base = 0; base < N_NODES; base += 1024) {
        int i = base + tid;
        int v = (i < N_NODES) ? cnt[i] : 0;
        if (i < N_NODES) dinv[i] = rsqrtf((float)v + 1.0f);
        int x = v;
        #pragma unroll
        for (int d = 1; d < 64; d <<= 1) {
            int y = __shfl_up(x, (unsigned)d);
            if (lane >= d) x += y;
        }
        if (lane == 63) wsum[wid] = x;
        __syncthreads();
        if (tid == 0) {
            int run = 0;
            for (int w = 0; w < 16; ++w) { int t = wsum[w]; wsum[w] = run; run += t; }
        }
        __syncthreads();
        int carry = s_carry;
        int excl = carry + wsum[wid] + (x - v);
        if (i < N_NODES) offs[i] = excl;
        __syncthreads();
        if (tid == 1023) s_carry = carry + wsum[15] + x;  // waves 0-14 excl + wave15 incl
        __syncthreads();
    }
    if (tid == 0) offs[N_NODES] = s_carry;
    __syncthreads();
    for (int b = tid; b < NB; b += 1024) bcur[b] = offs[b * BSZ];  // b*BSZ <= 49920 < N
}

// LDS multisplit by bucket (dst>>7): contiguous run writes (round-9 lesson: the
// per-position cursor scatter pays a full 64B line per 4B write — 81 MB; runs don't).
// binned[pos] = { (dst<<16)|src , bits(f32 dinv[src]) }  — bucket-grouped, unordered within.
__global__ __launch_bounds__(256) void k_bin(const int* __restrict__ esrc,
                                             const int* __restrict__ edst,
                                             const float* __restrict__ dinv,
                                             int* __restrict__ bcur,
                                             uint2* __restrict__ binned) {
    __shared__ int lcnt[NB];
    __shared__ int lbase[NB];
    int tid = threadIdx.x;
    for (int i = tid; i < NB; i += 256) lcnt[i] = 0;
    __syncthreads();
    int e0 = blockIdx.x * BIN_CHUNK;
    int myidx[32];  // (bucket<<16) | local_idx ; literal-indexed only (reg-resident)
    #pragma unroll
    for (int t = 0; t < 32; ++t) {
        int i = e0 + t * 256 + tid;
        if (i < N_EDGES) {
            int b = edst[i] >> 7;
            int idx = atomicAdd(&lcnt[b], 1);
            myidx[t] = (b << 16) | idx;
        }
    }
    __syncthreads();
    for (int b = tid; b < NB; b += 256)
        if (lcnt[b]) lbase[b] = atomicAdd(&bcur[b], lcnt[b]);
    __syncthreads();
    #pragma unroll
    for (int t = 0; t < 32; ++t) {
        int i = e0 + t * 256 + tid;
        if (i < N_EDGES) {
            int m = myidx[t];
            int b = m >> 16, idx = m & 0xFFFF;
            int s = esrc[i], d = edst[i];
            binned[lbase[b] + idx] =
                make_uint2(((unsigned)d << 16) | (unsigned)s, __float_as_int(dinv[s]));
        }
    }
}

// batch is sorted: gstart[g] = first node with batch >= g; gstart[N_GRAPHS] = N_NODES
__global__ void k_bounds(const int* __restrict__ batch, int* __restrict__ gstart) {
    int v = blockIdx.x * blockDim.x + threadIdx.x;
    if (v >= N_NODES) return;
    if (v == 0) {
        int b = batch[0];
        for (int g = 0; g <= b; ++g) gstart[g] = 0;
    } else {
        int b0 = batch[v - 1], b1 = batch[v];
        for (int g = b0 + 1; g <= b1; ++g) gstart[g] = v;
    }
    if (v == N_NODES - 1) {
        int b = batch[v];
        for (int g = b + 1; g <= N_GRAPHS; ++g) gstart[g] = N_NODES;
    }
}

// ---------------- dense layers ----------------

// out_bf[N,64] = bf16(A'[N,K] @ W[K,64]); 64x64 tile, 4x4 register micro-tile.
// NORM: A' = relu(A*sc[k] + sh[k]) — prev layer's BN+ReLU fused into the A-stage.
// __launch_bounds__(256,2) caps VGPR<=128; bounded unroll (round-6 spill lesson).
template <int K, bool NORM>
__global__ __launch_bounds__(256, 2) void k_gemm(const float* __restrict__ A,
                                                 const float* __restrict__ W,
                                                 unsigned short* __restrict__ out_bf,
                                                 const float* __restrict__ stats,
                                                 const float* __restrict__ gamma,
                                                 const float* __restrict__ beta) {
    __shared__ float sW[K * 64];
    __shared__ float sA[32][68];   // transposed A-chunk, +4 pad (aligned b128 reads)
    __shared__ float ssc[128];
    __shared__ float ssh[128];
    int tid = threadIdx.x;
    for (int i = tid; i < K * 16; i += 256) ((float4*)sW)[i] = ((const float4*)W)[i];
    if (NORM && tid < K) {
        const float invN = 1.0f / (float)N_NODES;
        float mu = stats[tid] * invN;
        float var = stats[64 + tid] * invN - mu * mu;
        float sc = rsqrtf(var + EPSF) * gamma[tid];
        ssc[tid] = sc;
        ssh[tid] = beta[tid] - mu * sc;
    }
    __syncthreads();

    int row0 = blockIdx.x * 64;
    int c0 = (tid & 15) * 4;
    int r0 = (tid >> 4) * 4;
    float acc[4][4] = {};

    #pragma unroll 1
    for (int k0 = 0; k0 < K; k0 += 32) {
        #pragma unroll
        for (int i = 0; i < 2; ++i) {
            int idx = tid + i * 256;          // [0,512): row = idx/8, kq = idx%8
            int row = idx >> 3;
            int kq = idx & 7;
            int grow = row0 + row;
            float4 v = make_float4(0.f, 0.f, 0.f, 0.f);
            if (grow < N_NODES) v = *(const float4*)&A[(size_t)grow * K + k0 + kq * 4];
            if (NORM) {
                int kb = k0 + kq * 4;
                v.x = fmaxf(v.x * ssc[kb + 0] + ssh[kb + 0], 0.f);
                v.y = fmaxf(v.y * ssc[kb + 1] + ssh[kb + 1], 0.f);
                v.z = fmaxf(v.z * ssc[kb + 2] + ssh[kb + 2], 0.f);
                v.w = fmaxf(v.w * ssc[kb + 3] + ssh[kb + 3], 0.f);
            }
            sA[kq * 4 + 0][row] = v.x;
            sA[kq * 4 + 1][row] = v.y;
            sA[kq * 4 + 2][row] = v.z;
            sA[kq * 4 + 3][row] = v.w;
        }
        __syncthreads();
        #pragma unroll 4
        for (int k = 0; k < 32; ++k) {
            float4 a = *(const float4*)&sA[k][r0];
            float4 w = *(const float4*)&sW[(k0 + k) * 64 + c0];
            acc[0][0] += a.x * w.x; acc[0][1] += a.x * w.y; acc[0][2] += a.x * w.z; acc[0][3] += a.x * w.w;
            acc[1][0] += a.y * w.x; acc[1][1] += a.y * w.y; acc[1][2] += a.y * w.z; acc[1][3] += a.y * w.w;
            acc[2][0] += a.z * w.x; acc[2][1] += a.z * w.y; acc[2][2] += a.z * w.z; acc[2][3] += a.z * w.w;
            acc[3][0] += a.w * w.x; acc[3][1] += a.w * w.y; acc[3][2] += a.w * w.z; acc[3][3] += a.w * w.w;
        }
        __syncthreads();
    }
    #pragma unroll
    for (int i = 0; i < 4; ++i) {
        int row = row0 + r0 + i;
        if (row < N_NODES) {
            ushort4 o;
            o.x = f2bf(acc[i][0]); o.y = f2bf(acc[i][1]);
            o.z = f2bf(acc[i][2]); o.w = f2bf(acc[i][3]);
            *(ushort4*)&out_bf[(size_t)row * 64 + c0] = o;  // 8B aligned (c0%4==0)
        }
    }
}

// One block per 128-node bucket: LDS accumulator acc[128][64]. Waves stream the
// bucket's contiguous binned edges; per edge: readlane-broadcast entry (uniform
// src/weight), coalesced 128B hw-row gather, conflict-free LDS float atomicAdd.
// Epilogue: hpre = dv*acc + dv^2*hw_v + b (coalesced) + block-reduced BN stats.
__global__ __launch_bounds__(1024) void k_aggb(const unsigned short* __restrict__ hw,
                                               const int* __restrict__ offs,
                                               const uint2* __restrict__ binned,
                                               const float* __restrict__ dinv,
                                               const float* __restrict__ bias,
                                               float* __restrict__ hpre,
                                               float* __restrict__ stats) {
    __shared__ float acc[BSZ * 64];   // 32 KB
    __shared__ float sred[128];
    int tid = threadIdx.x;
    int lane = tid & 63;
    int wid = tid >> 6;               // 16 waves
    int v0 = blockIdx.x * BSZ;
    int v1 = min(v0 + BSZ, N_NODES);
    int nn = v1 - v0;

    #pragma unroll
    for (int i = 0; i < 8; ++i) ((float4*)acc)[tid + i * 1024] = make_float4(0.f, 0.f, 0.f, 0.f);
    if (tid < 128) sred[tid] = 0.f;
    __syncthreads();

    int estart = offs[v0];
    int eend = offs[v1];

    for (int base = estart + wid * 64; base < eend; base += 1024) {
        unsigned ex = 0, ey = 0;
        if (base + lane < eend) {
            uint2 E = binned[base + lane];
            ex = E.x; ey = E.y;
        }
        int nt = min(64, eend - base);
        #pragma unroll 4
        for (int t = 0; t < nt; ++t) {
            unsigned px = (unsigned)__builtin_amdgcn_readlane((int)ex, t);
            float w = __uint_as_float((unsigned)__builtin_amdgcn_readlane((int)ey, t));
            int src = (int)(px & 0xFFFFu);
            int lv = (int)(px >> 16) - v0;
            float h = bf2f(hw[(size_t)src * 64 + lane]);
            atomicAdd(&acc[lv * 64 + lane], w * h);
        }
    }
    __syncthreads();

    float b = bias[lane];
    float lsum = 0.f, lsq = 0.f;
    for (int lv = wid; lv < nn; lv += 16) {
        int v = v0 + lv;
        float dv = dinv[v];
        float hv = bf2f(hw[(size_t)v * 64 + lane]);
        float a = dv * acc[lv * 64 + lane] + dv * dv * hv + b;
        hpre[(size_t)v * 64 + lane] = a;
        lsum += a;
        lsq += a * a;
    }
    atomicAdd(&sred[lane], lsum);
    atomicAdd(&sred[64 + lane], lsq);
    __syncthreads();
    if (tid < 128) atomicAdd(&stats[tid], sred[tid]);
}

// one block per graph: norm+relu layer-3 rows, register max/sum over the graph's
// contiguous node range, LDS tree-reduce, then fused head MLP. Zero atomics.
__global__ __launch_bounds__(256) void k_pool(const float* __restrict__ hpre,
                                              const float* __restrict__ stats,
                                              const float* __restrict__ gamma,
                                              const float* __restrict__ beta,
                                              const int* __restrict__ gstart,
                                              const float* __restrict__ lw1,
                                              const float* __restrict__ lb1,
                                              const float* __restrict__ lw2,
                                              const float* __restrict__ lb2,
                                              float* __restrict__ out) {
    __shared__ float smax[4][64];
    __shared__ float ssum[4][64];
    __shared__ float emb[192];
    __shared__ float hid[64];
    int g = blockIdx.x;
    int lane = threadIdx.x & 63;
    int wid = threadIdx.x >> 6;
    int s = gstart[g], e = gstart[g + 1];

    const float invN = 1.0f / (float)N_NODES;
    float mu = stats[lane] * invN;
    float var = stats[64 + lane] * invN - mu * mu;
    float sc = rsqrtf(var + EPSF) * gamma[lane];
    float sh = beta[lane] - mu * sc;

    float mx = 0.f, sm = 0.f;  // post-relu values are >= 0; empty graph -> 0 (matches ref)
    for (int v = s + wid; v < e; v += 4) {
        float h = fmaxf(hpre[(size_t)v * 64 + lane] * sc + sh, 0.f);
        mx = fmaxf(mx, h);
        sm += h;
    }
    smax[wid][lane] = mx;
    ssum[wid][lane] = sm;
    __syncthreads();
    if (wid == 0) {
        float m = fmaxf(fmaxf(smax[0][lane], smax[1][lane]), fmaxf(smax[2][lane], smax[3][lane]));
        float su = ssum[0][lane] + ssum[1][lane] + ssum[2][lane] + ssum[3][lane];
        float inv = 1.0f / fmaxf((float)(e - s), 1.0f);
        emb[lane] = m;
        emb[64 + lane] = su * inv;
        emb[128 + lane] = su;
    }
    __syncthreads();
    if (wid == 0) {
        float acc = lb1[lane];
        #pragma unroll 4
        for (int k = 0; k < 192; ++k) acc += emb[k] * lw1[k * 64 + lane];
        hid[lane] = fmaxf(acc, 0.f);
    }
    __syncthreads();
    if (threadIdx.x < N_CLASSES) {
        int j = threadIdx.x;
        float o = lb2[j];
        #pragma unroll 8
        for (int k = 0; k < 64; ++k) o += hid[k] * lw2[k * 10 + j];
        out[(size_t)g * 10 + j] = o;
    }
}

// ---------------- launch ----------------

extern "C" void kernel_launch(void* const* d_in, const int* in_sizes, int n_in,
                              void* d_out, int out_size, void* d_ws, size_t ws_size,
                              hipStream_t stream) {
    const float* x     = (const float*)d_in[0];
    const int* eidx    = (const int*)d_in[1];
    const int* batch   = (const int*)d_in[2];
    const float* W1    = (const float*)d_in[3];
    const float* b1    = (const float*)d_in[4];
    const float* W2    = (const float*)d_in[5];
    const float* b2    = (const float*)d_in[6];
    const float* gamma = (const float*)d_in[7];
    const float* beta  = (const float*)d_in[8];
    const float* lw1   = (const float*)d_in[9];
    const float* lb1   = (const float*)d_in[10];
    const float* lw2   = (const float*)d_in[11];
    const float* lb2   = (const float*)d_in[12];
    float* out = (float*)d_out;

    const int* e_src = eidx;
    const int* e_dst = eidx + N_EDGES;

    char* p = (char*)d_ws;
    auto carve = [&](size_t bytes) { char* r = p; p += (bytes + 255) & ~(size_t)255; return r; };
    // zero-initialized region (one memset covers these)
    int*   cnt   = (int*)carve((size_t)N_NODES * 4);
    float* stats = (float*)carve(3 * 128 * 4);
    size_t zero_bytes = (size_t)(p - (char*)d_ws);
    // scratch (no init needed)
    int*   offs   = (int*)carve((size_t)(N_NODES + 1) * 4);
    int*   bcur   = (int*)carve((size_t)NB * 4);
    float* dinv   = (float*)carve((size_t)N_NODES * 4);
    int*   gstart = (int*)carve((size_t)(N_GRAPHS + 1) * 4);
    uint2* binned = (uint2*)carve((size_t)N_EDGES * 8);
    unsigned short* B0 = (unsigned short*)carve((size_t)N_NODES * 64 * 2);  // bf16 h@W (gather src)
    float* B1     = (float*)carve((size_t)N_NODES * 64 * 4);                // fp32 h_pre

    hipMemsetAsync(d_ws, 0, zero_bytes, stream);

    // degree hist -> scan (offs, dinv, bucket bases) -> bucket multisplit
    k_hist<<<(N_EDGES + 255) / 256, 256, 0, stream>>>(e_dst, cnt);
    k_scan<<<1, 1024, 0, stream>>>(cnt, offs, bcur, dinv);
    k_bin<<<(N_EDGES + BIN_CHUNK - 1) / BIN_CHUNK, 256, 0, stream>>>(e_src, e_dst, dinv, bcur, binned);
    k_bounds<<<(N_NODES + 255) / 256, 256, 0, stream>>>(batch, gstart);

    const int GEMM_GRID = (N_NODES + 63) / 64;  // 782
    // layer 1
    k_gemm<128, false><<<GEMM_GRID, 256, 0, stream>>>(x, W1, B0, nullptr, nullptr, nullptr);
    k_aggb<<<NB, 1024, 0, stream>>>(B0, offs, binned, dinv, b1, B1, stats);
    // layer 2 (norm+relu of layer 1 fused into A-stage)
    k_gemm<64, true><<<GEMM_GRID, 256, 0, stream>>>(B1, W2, B0, stats, gamma, beta);
    k_aggb<<<NB, 1024, 0, stream>>>(B0, offs, binned, dinv, b2, B1, stats + 128);
    // layer 3 (norm+relu of layer 2 fused into A-stage)
    k_gemm<64, true><<<GEMM_GRID, 256, 0, stream>>>(B1, W2, B0, stats + 128, gamma, beta);
    k_aggb<<<NB, 1024, 0, stream>>>(B0, offs, binned, dinv, b2, B1, stats + 256);
    // norm+relu layer 3 + segmented pooling + head MLP (no atomics)
    k_pool<<<N_GRAPHS, 256, 0, stream>>>(B1, stats + 256, gamma, beta, gstart,
                                         lw1, lb1, lw2, lb2, out);
}

// Round 11
// 534.205 us; speedup vs baseline: 3.5258x; 3.5258x over previous
//
#include <hip/hip_runtime.h>
#include <hip/hip_bf16.h>

#define N_NODES 50000
#define N_EDGES 1200000
#define F_IN 128
#define HID 64
#define N_CLASSES 10
#define N_GRAPHS 256
#define EPSF 1e-5f

#define BSZ 128                     // nodes per bucket
#define NB 391                      // ceil(50000/128)
#define BIN_CHUNK 8192              // edges per k_bin block

__device__ __forceinline__ float bf2f(unsigned short u) {
    return __uint_as_float((unsigned)u << 16);
}
__device__ __forceinline__ unsigned short f2bf(float f) {
    __hip_bfloat16 h = __float2bfloat16(f);  // RNE
    return *reinterpret_cast<unsigned short*>(&h);
}

// ---------------- degree histogram ----------------

__global__ void k_hist(const int* __restrict__ dst, int* __restrict__ cnt) {
    int e = blockIdx.x * blockDim.x + threadIdx.x;
    if (e < N_EDGES) atomicAdd(&cnt[dst[e]], 1);
}

// single-block exclusive scan over N_NODES ints; emits dinv = rsqrt(cnt+1) and
// per-bucket cursor bases bcur[b] = offs[b*BSZ] (consumed by k_bin's run claims).
__global__ __launch_bounds__(1024) void k_scan(const int* __restrict__ cnt,
                                               int* __restrict__ offs,
                                               int* __restrict__ bcur,
                                               float* __restrict__ dinv) {
    __shared__ int wsum[16];
    __shared__ int s_carry;
    int tid = threadIdx.x;
    int lane = tid & 63, wid = tid >> 6;
    if (tid == 0) s_carry = 0;
    __syncthreads();
    for (int base = 0; base < N_NODES; base += 1024) {
        int i = base + tid;
        int v = (i < N_NODES) ? cnt[i] : 0;
        if (i < N_NODES) dinv[i] = rsqrtf((float)v + 1.0f);
        int x = v;
        #pragma unroll
        for (int d = 1; d < 64; d <<= 1) {
            int y = __shfl_up(x, (unsigned)d);
            if (lane >= d) x += y;
        }
        if (lane == 63) wsum[wid] = x;
        __syncthreads();
        if (tid == 0) {
            int run = 0;
            for (int w = 0; w < 16; ++w) { int t = wsum[w]; wsum[w] = run; run += t; }
        }
        __syncthreads();
        int carry = s_carry;
        int excl = carry + wsum[wid] + (x - v);
        if (i < N_NODES) offs[i] = excl;
        __syncthreads();
        if (tid == 1023) s_carry = carry + wsum[15] + x;  // waves 0-14 excl + wave15 incl
        __syncthreads();
    }
    if (tid == 0) offs[N_NODES] = s_carry;
    __syncthreads();
    for (int b = tid; b < NB; b += 1024) bcur[b] = offs[b * BSZ];  // b*BSZ <= 49920 < N
}

// Phase 1: LDS multisplit by bucket (dst>>7). Writes are contiguous runs —
// round-9 lesson: a global per-node cursor scatter pays a full 64B line per 4B
// write (81 MB, lines bounce across XCDs); runs don't.
// binned[pos] = { (dst<<16)|src , bits(f32 dinv[src]) }  — bucket-grouped.
__global__ __launch_bounds__(256) void k_bin(const int* __restrict__ esrc,
                                             const int* __restrict__ edst,
                                             const float* __restrict__ dinv,
                                             int* __restrict__ bcur,
                                             uint2* __restrict__ binned) {
    __shared__ int lcnt[NB];
    __shared__ int lbase[NB];
    int tid = threadIdx.x;
    for (int i = tid; i < NB; i += 256) lcnt[i] = 0;
    __syncthreads();
    int e0 = blockIdx.x * BIN_CHUNK;
    int myidx[32];  // (bucket<<16) | local_idx ; literal-indexed only (reg-resident)
    #pragma unroll
    for (int t = 0; t < 32; ++t) {
        int i = e0 + t * 256 + tid;
        if (i < N_EDGES) {
            int b = edst[i] >> 7;
            int idx = atomicAdd(&lcnt[b], 1);
            myidx[t] = (b << 16) | idx;
        }
    }
    __syncthreads();
    for (int b = tid; b < NB; b += 256)
        if (lcnt[b]) lbase[b] = atomicAdd(&bcur[b], lcnt[b]);
    __syncthreads();
    #pragma unroll
    for (int t = 0; t < 32; ++t) {
        int i = e0 + t * 256 + tid;
        if (i < N_EDGES) {
            int m = myidx[t];
            int b = m >> 16, idx = m & 0xFFFF;
            int s = esrc[i], d = edst[i];
            binned[lbase[b] + idx] =
                make_uint2(((unsigned)d << 16) | (unsigned)s, __float_as_int(dinv[s]));
        }
    }
}

// Phase 2: one block per bucket — read the bucket's contiguous binned run,
// LDS per-node cursors, scatter into the bucket's ~12KB csr window. All lines
// of that window are owned by this one CU -> L2-local, written back once.
// Output layout identical to round-9 csr: (bf16(dinv[src])<<16)|src, per-node runs.
__global__ __launch_bounds__(256) void k_fill2(const uint2* __restrict__ binned,
                                               const int* __restrict__ offs,
                                               unsigned int* __restrict__ csr) {
    __shared__ int cur[BSZ];
    int v0 = blockIdx.x * BSZ;
    int v1 = min(v0 + BSZ, N_NODES);
    int tid = threadIdx.x;
    for (int i = tid; i < BSZ; i += 256)
        cur[i] = (v0 + i < N_NODES) ? offs[v0 + i] : 0;
    __syncthreads();
    int s = offs[v0], e = offs[v1];
    for (int j = s + tid; j < e; j += 256) {
        uint2 E = binned[j];
        int lv = (int)(E.x >> 16) - v0;
        unsigned src = E.x & 0xFFFFu;
        int pos = atomicAdd(&cur[lv], 1);
        csr[pos] = ((unsigned)f2bf(__uint_as_float(E.y)) << 16) | src;
    }
}

// batch is sorted: gstart[g] = first node with batch >= g; gstart[N_GRAPHS] = N_NODES
__global__ void k_bounds(const int* __restrict__ batch, int* __restrict__ gstart) {
    int v = blockIdx.x * blockDim.x + threadIdx.x;
    if (v >= N_NODES) return;
    if (v == 0) {
        int b = batch[0];
        for (int g = 0; g <= b; ++g) gstart[g] = 0;
    } else {
        int b0 = batch[v - 1], b1 = batch[v];
        for (int g = b0 + 1; g <= b1; ++g) gstart[g] = v;
    }
    if (v == N_NODES - 1) {
        int b = batch[v];
        for (int g = b + 1; g <= N_GRAPHS; ++g) gstart[g] = N_NODES;
    }
}

// ---------------- dense layers ----------------

// out_bf[N,64] = bf16(A'[N,K] @ W[K,64]); 64x64 tile, 4x4 register micro-tile.
// NORM: A' = relu(A*sc[k] + sh[k]) — prev layer's BN+ReLU fused into the A-stage.
// __launch_bounds__(256,2) caps VGPR<=128; bounded unroll (round-6 spill lesson).
template <int K, bool NORM>
__global__ __launch_bounds__(256, 2) void k_gemm(const float* __restrict__ A,
                                                 const float* __restrict__ W,
                                                 unsigned short* __restrict__ out_bf,
                                                 const float* __restrict__ stats,
                                                 const float* __restrict__ gamma,
                                                 const float* __restrict__ beta) {
    __shared__ float sW[K * 64];
    __shared__ float sA[32][68];   // transposed A-chunk, +4 pad (aligned b128 reads)
    __shared__ float ssc[128];
    __shared__ float ssh[128];
    int tid = threadIdx.x;
    for (int i = tid; i < K * 16; i += 256) ((float4*)sW)[i] = ((const float4*)W)[i];
    if (NORM && tid < K) {
        const float invN = 1.0f / (float)N_NODES;
        float mu = stats[tid] * invN;
        float var = stats[64 + tid] * invN - mu * mu;
        float sc = rsqrtf(var + EPSF) * gamma[tid];
        ssc[tid] = sc;
        ssh[tid] = beta[tid] - mu * sc;
    }
    __syncthreads();

    int row0 = blockIdx.x * 64;
    int c0 = (tid & 15) * 4;
    int r0 = (tid >> 4) * 4;
    float acc[4][4] = {};

    #pragma unroll 1
    for (int k0 = 0; k0 < K; k0 += 32) {
        #pragma unroll
        for (int i = 0; i < 2; ++i) {
            int idx = tid + i * 256;          // [0,512): row = idx/8, kq = idx%8
            int row = idx >> 3;
            int kq = idx & 7;
            int grow = row0 + row;
            float4 v = make_float4(0.f, 0.f, 0.f, 0.f);
            if (grow < N_NODES) v = *(const float4*)&A[(size_t)grow * K + k0 + kq * 4];
            if (NORM) {
                int kb = k0 + kq * 4;
                v.x = fmaxf(v.x * ssc[kb + 0] + ssh[kb + 0], 0.f);
                v.y = fmaxf(v.y * ssc[kb + 1] + ssh[kb + 1], 0.f);
                v.z = fmaxf(v.z * ssc[kb + 2] + ssh[kb + 2], 0.f);
                v.w = fmaxf(v.w * ssc[kb + 3] + ssh[kb + 3], 0.f);
            }
            sA[kq * 4 + 0][row] = v.x;
            sA[kq * 4 + 1][row] = v.y;
            sA[kq * 4 + 2][row] = v.z;
            sA[kq * 4 + 3][row] = v.w;
        }
        __syncthreads();
        #pragma unroll 4
        for (int k = 0; k < 32; ++k) {
            float4 a = *(const float4*)&sA[k][r0];
            float4 w = *(const float4*)&sW[(k0 + k) * 64 + c0];
            acc[0][0] += a.x * w.x; acc[0][1] += a.x * w.y; acc[0][2] += a.x * w.z; acc[0][3] += a.x * w.w;
            acc[1][0] += a.y * w.x; acc[1][1] += a.y * w.y; acc[1][2] += a.y * w.z; acc[1][3] += a.y * w.w;
            acc[2][0] += a.z * w.x; acc[2][1] += a.z * w.y; acc[2][2] += a.z * w.z; acc[2][3] += a.z * w.w;
            acc[3][0] += a.w * w.x; acc[3][1] += a.w * w.y; acc[3][2] += a.w * w.z; acc[3][3] += a.w * w.w;
        }
        __syncthreads();
    }
    #pragma unroll
    for (int i = 0; i < 4; ++i) {
        int row = row0 + r0 + i;
        if (row < N_NODES) {
            ushort4 o;
            o.x = f2bf(acc[i][0]); o.y = f2bf(acc[i][1]);
            o.z = f2bf(acc[i][2]); o.w = f2bf(acc[i][3]);
            *(ushort4*)&out_bf[(size_t)row * 64 + c0] = o;  // 8B aligned (c0%4==0)
        }
    }
}

// hpre[v] = dv * (dv*hw[v] + sum_u w_u*hw[u]) + b ; hw bf16, accum fp32.
// Round-9 version verbatim (83 µs measured) — round-10's wave-cooperative
// bucket variant was 6x slower (serial per-edge chain, no MLP). Reverted.
__global__ __launch_bounds__(256) void k_agg(const unsigned short* __restrict__ hw,
                                             const int* __restrict__ offs,
                                             const unsigned int* __restrict__ csr,
                                             const float* __restrict__ dinv,
                                             const float* __restrict__ bias,
                                             float* __restrict__ hpre,
                                             float* __restrict__ stats) {
    __shared__ float sred[128];
    if (threadIdx.x < 128) sred[threadIdx.x] = 0.f;
    __syncthreads();
    int lane = threadIdx.x & 63;
    int wave = blockIdx.x * 4 + (threadIdx.x >> 6);
    int nw = gridDim.x * 4;
    float b = bias[lane];
    float lsum = 0.f, lsq = 0.f;
    for (int v = wave; v < N_NODES; v += nw) {
        float dv = dinv[v];
        int s = offs[v], e = offs[v + 1];
        float inner = dv * bf2f(hw[(size_t)v * 64 + lane]);
        int j = s;
        for (; j + 16 <= e; j += 16) {
            unsigned int q[16];
            #pragma unroll
            for (int t = 0; t < 16; ++t) q[t] = csr[j + t];
            float hh[16];
            #pragma unroll
            for (int t = 0; t < 16; ++t)
                hh[t] = bf2f(hw[(size_t)(q[t] & 0xFFFFu) * 64 + lane]);
            #pragma unroll
            for (int t = 0; t < 16; ++t)
                inner += bf2f((unsigned short)(q[t] >> 16)) * hh[t];
        }
        for (; j + 4 <= e; j += 4) {
            unsigned int q0 = csr[j], q1 = csr[j + 1], q2 = csr[j + 2], q3 = csr[j + 3];
            float h0 = bf2f(hw[(size_t)(q0 & 0xFFFFu) * 64 + lane]);
            float h1 = bf2f(hw[(size_t)(q1 & 0xFFFFu) * 64 + lane]);
            float h2 = bf2f(hw[(size_t)(q2 & 0xFFFFu) * 64 + lane]);
            float h3 = bf2f(hw[(size_t)(q3 & 0xFFFFu) * 64 + lane]);
            inner += bf2f((unsigned short)(q0 >> 16)) * h0;
            inner += bf2f((unsigned short)(q1 >> 16)) * h1;
            inner += bf2f((unsigned short)(q2 >> 16)) * h2;
            inner += bf2f((unsigned short)(q3 >> 16)) * h3;
        }
        for (; j < e; ++j) {
            unsigned int q = csr[j];
            inner += bf2f((unsigned short)(q >> 16)) * bf2f(hw[(size_t)(q & 0xFFFFu) * 64 + lane]);
        }
        float acc = dv * inner + b;
        hpre[(size_t)v * 64 + lane] = acc;
        lsum += acc;
        lsq += acc * acc;
    }
    atomicAdd(&sred[lane], lsum);
    atomicAdd(&sred[64 + lane], lsq);
    __syncthreads();
    if (threadIdx.x < 128) atomicAdd(&stats[threadIdx.x], sred[threadIdx.x]);
}

// one block per graph: norm+relu layer-3 rows, register max/sum over the graph's
// contiguous node range, LDS tree-reduce, then fused head MLP. Zero atomics.
__global__ __launch_bounds__(256) void k_pool(const float* __restrict__ hpre,
                                              const float* __restrict__ stats,
                                              const float* __restrict__ gamma,
                                              const float* __restrict__ beta,
                                              const int* __restrict__ gstart,
                                              const float* __restrict__ lw1,
                                              const float* __restrict__ lb1,
                                              const float* __restrict__ lw2,
                                              const float* __restrict__ lb2,
                                              float* __restrict__ out) {
    __shared__ float smax[4][64];
    __shared__ float ssum[4][64];
    __shared__ float emb[192];
    __shared__ float hid[64];
    int g = blockIdx.x;
    int lane = threadIdx.x & 63;
    int wid = threadIdx.x >> 6;
    int s = gstart[g], e = gstart[g + 1];

    const float invN = 1.0f / (float)N_NODES;
    float mu = stats[lane] * invN;
    float var = stats[64 + lane] * invN - mu * mu;
    float sc = rsqrtf(var + EPSF) * gamma[lane];
    float sh = beta[lane] - mu * sc;

    float mx = 0.f, sm = 0.f;  // post-relu values are >= 0; empty graph -> 0 (matches ref)
    for (int v = s + wid; v < e; v += 4) {
        float h = fmaxf(hpre[(size_t)v * 64 + lane] * sc + sh, 0.f);
        mx = fmaxf(mx, h);
        sm += h;
    }
    smax[wid][lane] = mx;
    ssum[wid][lane] = sm;
    __syncthreads();
    if (wid == 0) {
        float m = fmaxf(fmaxf(smax[0][lane], smax[1][lane]), fmaxf(smax[2][lane], smax[3][lane]));
        float su = ssum[0][lane] + ssum[1][lane] + ssum[2][lane] + ssum[3][lane];
        float inv = 1.0f / fmaxf((float)(e - s), 1.0f);
        emb[lane] = m;
        emb[64 + lane] = su * inv;
        emb[128 + lane] = su;
    }
    __syncthreads();
    if (wid == 0) {
        float acc = lb1[lane];
        #pragma unroll 4
        for (int k = 0; k < 192; ++k) acc += emb[k] * lw1[k * 64 + lane];
        hid[lane] = fmaxf(acc, 0.f);
    }
    __syncthreads();
    if (threadIdx.x < N_CLASSES) {
        int j = threadIdx.x;
        float o = lb2[j];
        #pragma unroll 8
        for (int k = 0; k < 64; ++k) o += hid[k] * lw2[k * 10 + j];
        out[(size_t)g * 10 + j] = o;
    }
}

// ---------------- launch ----------------

extern "C" void kernel_launch(void* const* d_in, const int* in_sizes, int n_in,
                              void* d_out, int out_size, void* d_ws, size_t ws_size,
                              hipStream_t stream) {
    const float* x     = (const float*)d_in[0];
    const int* eidx    = (const int*)d_in[1];
    const int* batch   = (const int*)d_in[2];
    const float* W1    = (const float*)d_in[3];
    const float* b1    = (const float*)d_in[4];
    const float* W2    = (const float*)d_in[5];
    const float* b2    = (const float*)d_in[6];
    const float* gamma = (const float*)d_in[7];
    const float* beta  = (const float*)d_in[8];
    const float* lw1   = (const float*)d_in[9];
    const float* lb1   = (const float*)d_in[10];
    const float* lw2   = (const float*)d_in[11];
    const float* lb2   = (const float*)d_in[12];
    float* out = (float*)d_out;

    const int* e_src = eidx;
    const int* e_dst = eidx + N_EDGES;

    char* p = (char*)d_ws;
    auto carve = [&](size_t bytes) { char* r = p; p += (bytes + 255) & ~(size_t)255; return r; };
    // zero-initialized region (one memset covers these)
    int*   cnt   = (int*)carve((size_t)N_NODES * 4);
    float* stats = (float*)carve(3 * 128 * 4);
    size_t zero_bytes = (size_t)(p - (char*)d_ws);
    // scratch (no init needed)
    int*   offs   = (int*)carve((size_t)(N_NODES + 1) * 4);
    int*   bcur   = (int*)carve((size_t)NB * 4);
    float* dinv   = (float*)carve((size_t)N_NODES * 4);
    int*   gstart = (int*)carve((size_t)(N_GRAPHS + 1) * 4);
    uint2* binned = (uint2*)carve((size_t)N_EDGES * 8);
    unsigned int* csr = (unsigned int*)carve((size_t)N_EDGES * 4);
    unsigned short* B0 = (unsigned short*)carve((size_t)N_NODES * 64 * 2);  // bf16 h@W (gather src)
    float* B1     = (float*)carve((size_t)N_NODES * 64 * 4);                // fp32 h_pre

    hipMemsetAsync(d_ws, 0, zero_bytes, stream);

    // degree hist -> scan -> bucket multisplit -> bucket-local csr scatter
    k_hist<<<(N_EDGES + 255) / 256, 256, 0, stream>>>(e_dst, cnt);
    k_scan<<<1, 1024, 0, stream>>>(cnt, offs, bcur, dinv);
    k_bin<<<(N_EDGES + BIN_CHUNK - 1) / BIN_CHUNK, 256, 0, stream>>>(e_src, e_dst, dinv, bcur, binned);
    k_fill2<<<NB, 256, 0, stream>>>(binned, offs, csr);
    k_bounds<<<(N_NODES + 255) / 256, 256, 0, stream>>>(batch, gstart);

    const int GEMM_GRID = (N_NODES + 63) / 64;  // 782
    // layer 1
    k_gemm<128, false><<<GEMM_GRID, 256, 0, stream>>>(x, W1, B0, nullptr, nullptr, nullptr);
    k_agg<<<2048, 256, 0, stream>>>(B0, offs, csr, dinv, b1, B1, stats);
    // layer 2 (norm+relu of layer 1 fused into A-stage)
    k_gemm<64, true><<<GEMM_GRID, 256, 0, stream>>>(B1, W2, B0, stats, gamma, beta);
    k_agg<<<2048, 256, 0, stream>>>(B0, offs, csr, dinv, b2, B1, stats + 128);
    // layer 3 (norm+relu of layer 2 fused into A-stage)
    k_gemm<64, true><<<GEMM_GRID, 256, 0, stream>>>(B1, W2, B0, stats + 128, gamma, beta);
    k_agg<<<2048, 256, 0, stream>>>(B0, offs, csr, dinv, b2, B1, stats + 256);
    // norm+relu layer 3 + segmented pooling + head MLP (no atomics)
    k_pool<<<N_GRAPHS, 256, 0, stream>>>(B1, stats + 256, gamma, beta, gstart,
                                         lw1, lb1, lw2, lb2, out);
}

// Round 12
// 520.039 us; speedup vs baseline: 3.6219x; 1.0272x over previous
//
#include <hip/hip_runtime.h>
#include <hip/hip_bf16.h>

#define N_NODES 50000
#define N_EDGES 1200000
#define F_IN 128
#define HID 64
#define N_CLASSES 10
#define N_GRAPHS 256
#define EPSF 1e-5f

#define BSZ 128                     // nodes per bucket
#define NB 391                      // ceil(50000/128)
#define BIN_CHUNK 8192              // edges per k_bin block

__device__ __forceinline__ float bf2f(unsigned short u) {
    return __uint_as_float((unsigned)u << 16);
}
__device__ __forceinline__ unsigned short f2bf(float f) {
    __hip_bfloat16 h = __float2bfloat16(f);  // RNE
    return *reinterpret_cast<unsigned short*>(&h);
}

// ---------------- degree histogram ----------------

__global__ void k_hist(const int* __restrict__ dst, int* __restrict__ cnt) {
    int e = blockIdx.x * blockDim.x + threadIdx.x;
    if (e < N_EDGES) atomicAdd(&cnt[dst[e]], 1);
}

// single-block exclusive scan over N_NODES ints; emits dinv = rsqrt(cnt+1) and
// per-bucket cursor bases bcur[b] = offs[b*BSZ] (consumed by k_bin's run claims).
__global__ __launch_bounds__(1024) void k_scan(const int* __restrict__ cnt,
                                               int* __restrict__ offs,
                                               int* __restrict__ bcur,
                                               float* __restrict__ dinv) {
    __shared__ int wsum[16];
    __shared__ int s_carry;
    int tid = threadIdx.x;
    int lane = tid & 63, wid = tid >> 6;
    if (tid == 0) s_carry = 0;
    __syncthreads();
    for (int base = 0; base < N_NODES; base += 1024) {
        int i = base + tid;
        int v = (i < N_NODES) ? cnt[i] : 0;
        if (i < N_NODES) dinv[i] = rsqrtf((float)v + 1.0f);
        int x = v;
        #pragma unroll
        for (int d = 1; d < 64; d <<= 1) {
            int y = __shfl_up(x, (unsigned)d);
            if (lane >= d) x += y;
        }
        if (lane == 63) wsum[wid] = x;
        __syncthreads();
        if (tid == 0) {
            int run = 0;
            for (int w = 0; w < 16; ++w) { int t = wsum[w]; wsum[w] = run; run += t; }
        }
        __syncthreads();
        int carry = s_carry;
        int excl = carry + wsum[wid] + (x - v);
        if (i < N_NODES) offs[i] = excl;
        __syncthreads();
        if (tid == 1023) s_carry = carry + wsum[15] + x;  // waves 0-14 excl + wave15 incl
        __syncthreads();
    }
    if (tid == 0) offs[N_NODES] = s_carry;
    __syncthreads();
    for (int b = tid; b < NB; b += 1024) bcur[b] = offs[b * BSZ];  // b*BSZ <= 49920 < N
}

// Phase 1: LDS multisplit by bucket (dst>>7). Writes are contiguous runs —
// round-9 lesson: a global per-node cursor scatter pays a full 64B line per 4B
// write (81 MB, lines bounce across XCDs); runs don't.
// binned[pos] = { (dst<<16)|src , bits(f32 dinv[src]) }  — bucket-grouped.
__global__ __launch_bounds__(256) void k_bin(const int* __restrict__ esrc,
                                             const int* __restrict__ edst,
                                             const float* __restrict__ dinv,
                                             int* __restrict__ bcur,
                                             uint2* __restrict__ binned) {
    __shared__ int lcnt[NB];
    __shared__ int lbase[NB];
    int tid = threadIdx.x;
    for (int i = tid; i < NB; i += 256) lcnt[i] = 0;
    __syncthreads();
    int e0 = blockIdx.x * BIN_CHUNK;
    int myidx[32];  // (bucket<<16) | local_idx ; literal-indexed only (reg-resident)
    #pragma unroll
    for (int t = 0; t < 32; ++t) {
        int i = e0 + t * 256 + tid;
        if (i < N_EDGES) {
            int b = edst[i] >> 7;
            int idx = atomicAdd(&lcnt[b], 1);
            myidx[t] = (b << 16) | idx;
        }
    }
    __syncthreads();
    for (int b = tid; b < NB; b += 256)
        if (lcnt[b]) lbase[b] = atomicAdd(&bcur[b], lcnt[b]);
    __syncthreads();
    #pragma unroll
    for (int t = 0; t < 32; ++t) {
        int i = e0 + t * 256 + tid;
        if (i < N_EDGES) {
            int m = myidx[t];
            int b = m >> 16, idx = m & 0xFFFF;
            int s = esrc[i], d = edst[i];
            binned[lbase[b] + idx] =
                make_uint2(((unsigned)d << 16) | (unsigned)s, __float_as_int(dinv[s]));
        }
    }
}

// Phase 2: one block per bucket — read the bucket's contiguous binned run,
// LDS per-node cursors, scatter into the bucket's ~12KB csr window. All lines
// of that window are owned by this one CU -> L2-local, written back once.
__global__ __launch_bounds__(256) void k_fill2(const uint2* __restrict__ binned,
                                               const int* __restrict__ offs,
                                               unsigned int* __restrict__ csr) {
    __shared__ int cur[BSZ];
    int v0 = blockIdx.x * BSZ;
    int v1 = min(v0 + BSZ, N_NODES);
    int tid = threadIdx.x;
    for (int i = tid; i < BSZ; i += 256)
        cur[i] = (v0 + i < N_NODES) ? offs[v0 + i] : 0;
    __syncthreads();
    int s = offs[v0], e = offs[v1];
    for (int j = s + tid; j < e; j += 256) {
        uint2 E = binned[j];
        int lv = (int)(E.x >> 16) - v0;
        unsigned src = E.x & 0xFFFFu;
        int pos = atomicAdd(&cur[lv], 1);
        csr[pos] = ((unsigned)f2bf(__uint_as_float(E.y)) << 16) | src;
    }
}

// batch is sorted: gstart[g] = first node with batch >= g; gstart[N_GRAPHS] = N_NODES
__global__ void k_bounds(const int* __restrict__ batch, int* __restrict__ gstart) {
    int v = blockIdx.x * blockDim.x + threadIdx.x;
    if (v >= N_NODES) return;
    if (v == 0) {
        int b = batch[0];
        for (int g = 0; g <= b; ++g) gstart[g] = 0;
    } else {
        int b0 = batch[v - 1], b1 = batch[v];
        for (int g = b0 + 1; g <= b1; ++g) gstart[g] = v;
    }
    if (v == N_NODES - 1) {
        int b = batch[v];
        for (int g = b + 1; g <= N_GRAPHS; ++g) gstart[g] = N_NODES;
    }
}

// ---------------- dense layers ----------------

// out_bf[N,64] = bf16(A'[N,K] @ W[K,64]); 64x64 tile, 4x4 register micro-tile.
// NORM: A' = relu(A*sc[k] + sh[k]) — prev layer's BN+ReLU fused into the A-stage.
// __launch_bounds__(256,2) caps VGPR<=128; bounded unroll (round-6 spill lesson).
template <int K, bool NORM>
__global__ __launch_bounds__(256, 2) void k_gemm(const float* __restrict__ A,
                                                 const float* __restrict__ W,
                                                 unsigned short* __restrict__ out_bf,
                                                 const float* __restrict__ stats,
                                                 const float* __restrict__ gamma,
                                                 const float* __restrict__ beta) {
    __shared__ float sW[K * 64];
    __shared__ float sA[32][68];   // transposed A-chunk, +4 pad (aligned b128 reads)
    __shared__ float ssc[128];
    __shared__ float ssh[128];
    int tid = threadIdx.x;
    for (int i = tid; i < K * 16; i += 256) ((float4*)sW)[i] = ((const float4*)W)[i];
    if (NORM && tid < K) {
        const float invN = 1.0f / (float)N_NODES;
        float mu = stats[tid] * invN;
        float var = stats[64 + tid] * invN - mu * mu;
        float sc = rsqrtf(var + EPSF) * gamma[tid];
        ssc[tid] = sc;
        ssh[tid] = beta[tid] - mu * sc;
    }
    __syncthreads();

    int row0 = blockIdx.x * 64;
    int c0 = (tid & 15) * 4;
    int r0 = (tid >> 4) * 4;
    float acc[4][4] = {};

    #pragma unroll 1
    for (int k0 = 0; k0 < K; k0 += 32) {
        #pragma unroll
        for (int i = 0; i < 2; ++i) {
            int idx = tid + i * 256;          // [0,512): row = idx/8, kq = idx%8
            int row = idx >> 3;
            int kq = idx & 7;
            int grow = row0 + row;
            float4 v = make_float4(0.f, 0.f, 0.f, 0.f);
            if (grow < N_NODES) v = *(const float4*)&A[(size_t)grow * K + k0 + kq * 4];
            if (NORM) {
                int kb = k0 + kq * 4;
                v.x = fmaxf(v.x * ssc[kb + 0] + ssh[kb + 0], 0.f);
                v.y = fmaxf(v.y * ssc[kb + 1] + ssh[kb + 1], 0.f);
                v.z = fmaxf(v.z * ssc[kb + 2] + ssh[kb + 2], 0.f);
                v.w = fmaxf(v.w * ssc[kb + 3] + ssh[kb + 3], 0.f);
            }
            sA[kq * 4 + 0][row] = v.x;
            sA[kq * 4 + 1][row] = v.y;
            sA[kq * 4 + 2][row] = v.z;
            sA[kq * 4 + 3][row] = v.w;
        }
        __syncthreads();
        #pragma unroll 4
        for (int k = 0; k < 32; ++k) {
            float4 a = *(const float4*)&sA[k][r0];
            float4 w = *(const float4*)&sW[(k0 + k) * 64 + c0];
            acc[0][0] += a.x * w.x; acc[0][1] += a.x * w.y; acc[0][2] += a.x * w.z; acc[0][3] += a.x * w.w;
            acc[1][0] += a.y * w.x; acc[1][1] += a.y * w.y; acc[1][2] += a.y * w.z; acc[1][3] += a.y * w.w;
            acc[2][0] += a.z * w.x; acc[2][1] += a.z * w.y; acc[2][2] += a.z * w.z; acc[2][3] += a.z * w.w;
            acc[3][0] += a.w * w.x; acc[3][1] += a.w * w.y; acc[3][2] += a.w * w.z; acc[3][3] += a.w * w.w;
        }
        __syncthreads();
    }
    #pragma unroll
    for (int i = 0; i < 4; ++i) {
        int row = row0 + r0 + i;
        if (row < N_NODES) {
            ushort4 o;
            o.x = f2bf(acc[i][0]); o.y = f2bf(acc[i][1]);
            o.z = f2bf(acc[i][2]); o.w = f2bf(acc[i][3]);
            *(ushort4*)&out_bf[(size_t)row * 64 + c0] = o;  // 8B aligned (c0%4==0)
        }
    }
}

// hpre[v] = dv * (dv*hw[v] + sum_u w_u*hw[u]) + b ; hw bf16, accum fp32.
// 4-edges-per-instruction: lane loads ushort4 (4 features); the wave's four
// 16-lane groups process 4 DIFFERENT edges per gather (512B/instr vs 128B).
// Per edge: 0.5 VMEM + ~3.5 VALU (was 2 VMEM + ~7 VALU). Tail is branchless
// (index clamp + weight zeroing). Cross-group combine: 2x shfl_xor.
__global__ __launch_bounds__(256) void k_agg(const unsigned short* __restrict__ hw,
                                             const int* __restrict__ offs,
                                             const unsigned int* __restrict__ csr,
                                             const float* __restrict__ dinv,
                                             const float* __restrict__ bias,
                                             float* __restrict__ hpre,
                                             float* __restrict__ stats) {
    __shared__ float sred[128];
    if (threadIdx.x < 128) sred[threadIdx.x] = 0.f;
    __syncthreads();
    int lane = threadIdx.x & 63;
    int fq = lane & 15;   // feature quad: features 4*fq .. 4*fq+3
    int eg = lane >> 4;   // edge group 0..3
    int wave = blockIdx.x * 4 + (threadIdx.x >> 6);
    int nw = gridDim.x * 4;
    const ushort4* hw4 = (const ushort4*)hw;   // row v = hw4[v*16 + fq]
    float4 b4 = *(const float4*)&bias[fq * 4];
    float sx = 0.f, sy = 0.f, sz = 0.f, sw = 0.f;      // lsum per feature quad
    float qx = 0.f, qy = 0.f, qz = 0.f, qw = 0.f;      // lsq per feature quad
    for (int v = wave; v < N_NODES; v += nw) {
        float dv = dinv[v];
        int s = offs[v], e = offs[v + 1];
        float ax = 0.f, ay = 0.f, az = 0.f, aw = 0.f;
        for (int j = s; j < e; j += 16) {
            #pragma unroll
            for (int t = 0; t < 4; ++t) {
                int idx = j + 4 * t + eg;
                unsigned q = csr[min(idx, e - 1)];
                float w = __uint_as_float(q & 0xFFFF0000u);  // bf16 weight in high half
                w = (idx < e) ? w : 0.f;
                ushort4 h = hw4[(size_t)(q & 0xFFFFu) * 16 + fq];
                ax += w * bf2f(h.x);
                ay += w * bf2f(h.y);
                az += w * bf2f(h.z);
                aw += w * bf2f(h.w);
            }
        }
        // combine the 4 edge-groups (all lanes end with the full sum)
        #pragma unroll
        for (int m = 16; m < 64; m <<= 1) {
            ax += __shfl_xor(ax, m);
            ay += __shfl_xor(ay, m);
            az += __shfl_xor(az, m);
            aw += __shfl_xor(aw, m);
        }
        ushort4 hv = hw4[(size_t)v * 16 + fq];
        float dv2 = dv * dv;
        float rx = dv * ax + dv2 * bf2f(hv.x) + b4.x;
        float ry = dv * ay + dv2 * bf2f(hv.y) + b4.y;
        float rz = dv * az + dv2 * bf2f(hv.z) + b4.z;
        float rw = dv * aw + dv2 * bf2f(hv.w) + b4.w;
        if (lane < 16)
            *(float4*)&hpre[(size_t)v * 64 + fq * 4] = make_float4(rx, ry, rz, rw);
        sx += rx; sy += ry; sz += rz; sw += rw;
        qx += rx * rx; qy += ry * ry; qz += rz * rz; qw += rw * rw;
    }
    if (lane < 16) {  // groups 1-3 hold identical copies — count once
        atomicAdd(&sred[4 * fq + 0], sx);
        atomicAdd(&sred[4 * fq + 1], sy);
        atomicAdd(&sred[4 * fq + 2], sz);
        atomicAdd(&sred[4 * fq + 3], sw);
        atomicAdd(&sred[64 + 4 * fq + 0], qx);
        atomicAdd(&sred[64 + 4 * fq + 1], qy);
        atomicAdd(&sred[64 + 4 * fq + 2], qz);
        atomicAdd(&sred[64 + 4 * fq + 3], qw);
    }
    __syncthreads();
    if (threadIdx.x < 128) atomicAdd(&stats[threadIdx.x], sred[threadIdx.x]);
}

// one block per graph: norm+relu layer-3 rows, register max/sum over the graph's
// contiguous node range, LDS tree-reduce, then fused head MLP. Zero atomics.
__global__ __launch_bounds__(256) void k_pool(const float* __restrict__ hpre,
                                              const float* __restrict__ stats,
                                              const float* __restrict__ gamma,
                                              const float* __restrict__ beta,
                                              const int* __restrict__ gstart,
                                              const float* __restrict__ lw1,
                                              const float* __restrict__ lb1,
                                              const float* __restrict__ lw2,
                                              const float* __restrict__ lb2,
                                              float* __restrict__ out) {
    __shared__ float smax[4][64];
    __shared__ float ssum[4][64];
    __shared__ float emb[192];
    __shared__ float hid[64];
    int g = blockIdx.x;
    int lane = threadIdx.x & 63;
    int wid = threadIdx.x >> 6;
    int s = gstart[g], e = gstart[g + 1];

    const float invN = 1.0f / (float)N_NODES;
    float mu = stats[lane] * invN;
    float var = stats[64 + lane] * invN - mu * mu;
    float sc = rsqrtf(var + EPSF) * gamma[lane];
    float sh = beta[lane] - mu * sc;

    float mx = 0.f, sm = 0.f;  // post-relu values are >= 0; empty graph -> 0 (matches ref)
    for (int v = s + wid; v < e; v += 4) {
        float h = fmaxf(hpre[(size_t)v * 64 + lane] * sc + sh, 0.f);
        mx = fmaxf(mx, h);
        sm += h;
    }
    smax[wid][lane] = mx;
    ssum[wid][lane] = sm;
    __syncthreads();
    if (wid == 0) {
        float m = fmaxf(fmaxf(smax[0][lane], smax[1][lane]), fmaxf(smax[2][lane], smax[3][lane]));
        float su = ssum[0][lane] + ssum[1][lane] + ssum[2][lane] + ssum[3][lane];
        float inv = 1.0f / fmaxf((float)(e - s), 1.0f);
        emb[lane] = m;
        emb[64 + lane] = su * inv;
        emb[128 + lane] = su;
    }
    __syncthreads();
    if (wid == 0) {
        float acc = lb1[lane];
        #pragma unroll 4
        for (int k = 0; k < 192; ++k) acc += emb[k] * lw1[k * 64 + lane];
        hid[lane] = fmaxf(acc, 0.f);
    }
    __syncthreads();
    if (threadIdx.x < N_CLASSES) {
        int j = threadIdx.x;
        float o = lb2[j];
        #pragma unroll 8
        for (int k = 0; k < 64; ++k) o += hid[k] * lw2[k * 10 + j];
        out[(size_t)g * 10 + j] = o;
    }
}

// ---------------- launch ----------------

extern "C" void kernel_launch(void* const* d_in, const int* in_sizes, int n_in,
                              void* d_out, int out_size, void* d_ws, size_t ws_size,
                              hipStream_t stream) {
    const float* x     = (const float*)d_in[0];
    const int* eidx    = (const int*)d_in[1];
    const int* batch   = (const int*)d_in[2];
    const float* W1    = (const float*)d_in[3];
    const float* b1    = (const float*)d_in[4];
    const float* W2    = (const float*)d_in[5];
    const float* b2    = (const float*)d_in[6];
    const float* gamma = (const float*)d_in[7];
    const float* beta  = (const float*)d_in[8];
    const float* lw1   = (const float*)d_in[9];
    const float* lb1   = (const float*)d_in[10];
    const float* lw2   = (const float*)d_in[11];
    const float* lb2   = (const float*)d_in[12];
    float* out = (float*)d_out;

    const int* e_src = eidx;
    const int* e_dst = eidx + N_EDGES;

    char* p = (char*)d_ws;
    auto carve = [&](size_t bytes) { char* r = p; p += (bytes + 255) & ~(size_t)255; return r; };
    // zero-initialized region (one memset covers these)
    int*   cnt   = (int*)carve((size_t)N_NODES * 4);
    float* stats = (float*)carve(3 * 128 * 4);
    size_t zero_bytes = (size_t)(p - (char*)d_ws);
    // scratch (no init needed)
    int*   offs   = (int*)carve((size_t)(N_NODES + 1) * 4);
    int*   bcur   = (int*)carve((size_t)NB * 4);
    float* dinv   = (float*)carve((size_t)N_NODES * 4);
    int*   gstart = (int*)carve((size_t)(N_GRAPHS + 1) * 4);
    uint2* binned = (uint2*)carve((size_t)N_EDGES * 8);
    unsigned int* csr = (unsigned int*)carve((size_t)N_EDGES * 4);
    unsigned short* B0 = (unsigned short*)carve((size_t)N_NODES * 64 * 2);  // bf16 h@W (gather src)
    float* B1     = (float*)carve((size_t)N_NODES * 64 * 4);                // fp32 h_pre

    hipMemsetAsync(d_ws, 0, zero_bytes, stream);

    // degree hist -> scan -> bucket multisplit -> bucket-local csr scatter
    k_hist<<<(N_EDGES + 255) / 256, 256, 0, stream>>>(e_dst, cnt);
    k_scan<<<1, 1024, 0, stream>>>(cnt, offs, bcur, dinv);
    k_bin<<<(N_EDGES + BIN_CHUNK - 1) / BIN_CHUNK, 256, 0, stream>>>(e_src, e_dst, dinv, bcur, binned);
    k_fill2<<<NB, 256, 0, stream>>>(binned, offs, csr);
    k_bounds<<<(N_NODES + 255) / 256, 256, 0, stream>>>(batch, gstart);

    const int GEMM_GRID = (N_NODES + 63) / 64;  // 782
    // layer 1
    k_gemm<128, false><<<GEMM_GRID, 256, 0, stream>>>(x, W1, B0, nullptr, nullptr, nullptr);
    k_agg<<<2048, 256, 0, stream>>>(B0, offs, csr, dinv, b1, B1, stats);
    // layer 2 (norm+relu of layer 1 fused into A-stage)
    k_gemm<64, true><<<GEMM_GRID, 256, 0, stream>>>(B1, W2, B0, stats, gamma, beta);
    k_agg<<<2048, 256, 0, stream>>>(B0, offs, csr, dinv, b2, B1, stats + 128);
    // layer 3 (norm+relu of layer 2 fused into A-stage)
    k_gemm<64, true><<<GEMM_GRID, 256, 0, stream>>>(B1, W2, B0, stats + 128, gamma, beta);
    k_agg<<<2048, 256, 0, stream>>>(B0, offs, csr, dinv, b2, B1, stats + 256);
    // norm+relu layer 3 + segmented pooling + head MLP (no atomics)
    k_pool<<<N_GRAPHS, 256, 0, stream>>>(B1, stats + 256, gamma, beta, gstart,
                                         lw1, lb1, lw2, lb2, out);
}

// Round 15
// 506.077 us; speedup vs baseline: 3.7218x; 1.0276x over previous
//
#include <hip/hip_runtime.h>
#include <hip/hip_bf16.h>

#define N_NODES 50000
#define N_EDGES 1200000
#define F_IN 128
#define HID 64
#define N_CLASSES 10
#define N_GRAPHS 256
#define EPSF 1e-5f

#define BSZ 128                     // nodes per bucket
#define NB 391                      // ceil(50000/128)
#define BIN_CHUNK 8192              // edges per k_bin block
#define AGG_GRID 1792               // 7 blocks/CU — fits one scheduling round (r12 lesson:
                                    // 2048 = exact capacity -> two 50%-occupancy rounds)

__device__ __forceinline__ float bf2f(unsigned short u) {
    return __uint_as_float((unsigned)u << 16);
}
__device__ __forceinline__ unsigned short f2bf(float f) {
    __hip_bfloat16 h = __float2bfloat16(f);  // RNE
    return *reinterpret_cast<unsigned short*>(&h);
}

// ---------------- degree histogram ----------------

__global__ void k_hist(const int* __restrict__ dst, int* __restrict__ cnt) {
    int e = blockIdx.x * blockDim.x + threadIdx.x;
    if (e < N_EDGES) atomicAdd(&cnt[dst[e]], 1);
}

// single-block exclusive scan over N_NODES ints; emits dinv = rsqrt(cnt+1) and
// per-bucket cursor bases bcur[b] = offs[b*BSZ] (consumed by k_bin's run claims).
__global__ __launch_bounds__(1024) void k_scan(const int* __restrict__ cnt,
                                               int* __restrict__ offs,
                                               int* __restrict__ bcur,
                                               float* __restrict__ dinv) {
    __shared__ int wsum[16];
    __shared__ int s_carry;
    int tid = threadIdx.x;
    int lane = tid & 63, wid = tid >> 6;
    if (tid == 0) s_carry = 0;
    __syncthreads();
    for (int base = 0; base < N_NODES; base += 1024) {
        int i = base + tid;
        int v = (i < N_NODES) ? cnt[i] : 0;
        if (i < N_NODES) dinv[i] = rsqrtf((float)v + 1.0f);
        int x = v;
        #pragma unroll
        for (int d = 1; d < 64; d <<= 1) {
            int y = __shfl_up(x, (unsigned)d);
            if (lane >= d) x += y;
        }
        if (lane == 63) wsum[wid] = x;
        __syncthreads();
        if (tid == 0) {
            int run = 0;
            for (int w = 0; w < 16; ++w) { int t = wsum[w]; wsum[w] = run; run += t; }
        }
        __syncthreads();
        int carry = s_carry;
        int excl = carry + wsum[wid] + (x - v);
        if (i < N_NODES) offs[i] = excl;
        __syncthreads();
        if (tid == 1023) s_carry = carry + wsum[15] + x;  // waves 0-14 excl + wave15 incl
        __syncthreads();
    }
    if (tid == 0) offs[N_NODES] = s_carry;
    __syncthreads();
    for (int b = tid; b < NB; b += 1024) bcur[b] = offs[b * BSZ];  // b*BSZ <= 49920 < N
}

// Phase 1: LDS multisplit by bucket (dst>>7). Writes are contiguous runs —
// round-9 lesson: a global per-node cursor scatter pays a full 64B line per 4B
// write (81 MB, lines bounce across XCDs); runs don't.
__global__ __launch_bounds__(256) void k_bin(const int* __restrict__ esrc,
                                             const int* __restrict__ edst,
                                             const float* __restrict__ dinv,
                                             int* __restrict__ bcur,
                                             uint2* __restrict__ binned) {
    __shared__ int lcnt[NB];
    __shared__ int lbase[NB];
    int tid = threadIdx.x;
    for (int i = tid; i < NB; i += 256) lcnt[i] = 0;
    __syncthreads();
    int e0 = blockIdx.x * BIN_CHUNK;
    int myidx[32];  // (bucket<<16) | local_idx ; literal-indexed only (reg-resident)
    #pragma unroll
    for (int t = 0; t < 32; ++t) {
        int i = e0 + t * 256 + tid;
        if (i < N_EDGES) {
            int b = edst[i] >> 7;
            int idx = atomicAdd(&lcnt[b], 1);
            myidx[t] = (b << 16) | idx;
        }
    }
    __syncthreads();
    for (int b = tid; b < NB; b += 256)
        if (lcnt[b]) lbase[b] = atomicAdd(&bcur[b], lcnt[b]);
    __syncthreads();
    #pragma unroll
    for (int t = 0; t < 32; ++t) {
        int i = e0 + t * 256 + tid;
        if (i < N_EDGES) {
            int m = myidx[t];
            int b = m >> 16, idx = m & 0xFFFF;
            int s = esrc[i], d = edst[i];
            binned[lbase[b] + idx] =
                make_uint2(((unsigned)d << 16) | (unsigned)s, __float_as_int(dinv[s]));
        }
    }
}

// Phase 2: one block per bucket — read the bucket's contiguous binned run,
// LDS per-node cursors, scatter into the bucket's ~12KB csr window (L2-local).
__global__ __launch_bounds__(256) void k_fill2(const uint2* __restrict__ binned,
                                               const int* __restrict__ offs,
                                               unsigned int* __restrict__ csr) {
    __shared__ int cur[BSZ];
    int v0 = blockIdx.x * BSZ;
    int v1 = min(v0 + BSZ, N_NODES);
    int tid = threadIdx.x;
    for (int i = tid; i < BSZ; i += 256)
        cur[i] = (v0 + i < N_NODES) ? offs[v0 + i] : 0;
    __syncthreads();
    int s = offs[v0], e = offs[v1];
    for (int j = s + tid; j < e; j += 256) {
        uint2 E = binned[j];
        int lv = (int)(E.x >> 16) - v0;
        unsigned src = E.x & 0xFFFFu;
        int pos = atomicAdd(&cur[lv], 1);
        csr[pos] = ((unsigned)f2bf(__uint_as_float(E.y)) << 16) | src;
    }
}

// batch is sorted: gstart[g] = first node with batch >= g; gstart[N_GRAPHS] = N_NODES
__global__ void k_bounds(const int* __restrict__ batch, int* __restrict__ gstart) {
    int v = blockIdx.x * blockDim.x + threadIdx.x;
    if (v >= N_NODES) return;
    if (v == 0) {
        int b = batch[0];
        for (int g = 0; g <= b; ++g) gstart[g] = 0;
    } else {
        int b0 = batch[v - 1], b1 = batch[v];
        for (int g = b0 + 1; g <= b1; ++g) gstart[g] = v;
    }
    if (v == N_NODES - 1) {
        int b = batch[v];
        for (int g = b + 1; g <= N_GRAPHS; ++g) gstart[g] = N_NODES;
    }
}

// ---------------- dense layers ----------------

// out_bf[N,64] = bf16(A'[N,K] @ W[K,64]); 64x64 tile, 4x4 register micro-tile.
// NORM: A is bf16 hpre; A' = relu(A*sc[k] + sh[k]) fused into the A-stage.
// !NORM: A is fp32 x (layer 1, K=128).
// __launch_bounds__(256,2) caps VGPR<=128; bounded unroll (round-6 spill lesson).
template <int K, bool NORM>
__global__ __launch_bounds__(256, 2) void k_gemm(const void* __restrict__ Avoid,
                                                 const float* __restrict__ W,
                                                 unsigned short* __restrict__ out_bf,
                                                 const float* __restrict__ stats,
                                                 const float* __restrict__ gamma,
                                                 const float* __restrict__ beta) {
    __shared__ float sW[K * 64];
    __shared__ float sA[32][68];   // transposed A-chunk, +4 pad (aligned b128 reads)
    __shared__ float ssc[128];
    __shared__ float ssh[128];
    int tid = threadIdx.x;
    for (int i = tid; i < K * 16; i += 256) ((float4*)sW)[i] = ((const float4*)W)[i];
    if (NORM && tid < K) {
        const float invN = 1.0f / (float)N_NODES;
        float mu = stats[tid] * invN;
        float var = stats[64 + tid] * invN - mu * mu;
        float sc = rsqrtf(var + EPSF) * gamma[tid];
        ssc[tid] = sc;
        ssh[tid] = beta[tid] - mu * sc;
    }
    __syncthreads();

    int row0 = blockIdx.x * 64;
    int c0 = (tid & 15) * 4;
    int r0 = (tid >> 4) * 4;
    float acc[4][4] = {};

    #pragma unroll 1
    for (int k0 = 0; k0 < K; k0 += 32) {
        #pragma unroll
        for (int i = 0; i < 2; ++i) {
            int idx = tid + i * 256;          // [0,512): row = idx/8, kq = idx%8
            int row = idx >> 3;
            int kq = idx & 7;
            int grow = row0 + row;
            float4 v;
            if constexpr (NORM) {
                const unsigned short* Ab = (const unsigned short*)Avoid;
                ushort4 hv = make_ushort4(0, 0, 0, 0);
                if (grow < N_NODES) hv = *(const ushort4*)&Ab[(size_t)grow * K + k0 + kq * 4];
                v = make_float4(bf2f(hv.x), bf2f(hv.y), bf2f(hv.z), bf2f(hv.w));
                int kb = k0 + kq * 4;
                v.x = fmaxf(v.x * ssc[kb + 0] + ssh[kb + 0], 0.f);
                v.y = fmaxf(v.y * ssc[kb + 1] + ssh[kb + 1], 0.f);
                v.z = fmaxf(v.z * ssc[kb + 2] + ssh[kb + 2], 0.f);
                v.w = fmaxf(v.w * ssc[kb + 3] + ssh[kb + 3], 0.f);
            } else {
                const float* Af = (const float*)Avoid;
                v = make_float4(0.f, 0.f, 0.f, 0.f);
                if (grow < N_NODES) v = *(const float4*)&Af[(size_t)grow * K + k0 + kq * 4];
            }
            sA[kq * 4 + 0][row] = v.x;
            sA[kq * 4 + 1][row] = v.y;
            sA[kq * 4 + 2][row] = v.z;
            sA[kq * 4 + 3][row] = v.w;
        }
        __syncthreads();
        #pragma unroll 4
        for (int k = 0; k < 32; ++k) {
            float4 a = *(const float4*)&sA[k][r0];
            float4 w = *(const float4*)&sW[(k0 + k) * 64 + c0];
            acc[0][0] += a.x * w.x; acc[0][1] += a.x * w.y; acc[0][2] += a.x * w.z; acc[0][3] += a.x * w.w;
            acc[1][0] += a.y * w.x; acc[1][1] += a.y * w.y; acc[1][2] += a.y * w.z; acc[1][3] += a.y * w.w;
            acc[2][0] += a.z * w.x; acc[2][1] += a.z * w.y; acc[2][2] += a.z * w.z; acc[2][3] += a.z * w.w;
            acc[3][0] += a.w * w.x; acc[3][1] += a.w * w.y; acc[3][2] += a.w * w.z; acc[3][3] += a.w * w.w;
        }
        __syncthreads();
    }
    #pragma unroll
    for (int i = 0; i < 4; ++i) {
        int row = row0 + r0 + i;
        if (row < N_NODES) {
            ushort4 o;
            o.x = f2bf(acc[i][0]); o.y = f2bf(acc[i][1]);
            o.z = f2bf(acc[i][2]); o.w = f2bf(acc[i][3]);
            *(ushort4*)&out_bf[(size_t)row * 64 + c0] = o;  // 8B aligned (c0%4==0)
        }
    }
}

// hpre[v] = dv * (dv*hw[v] + sum_u w_u*hw[u]) + b ; hw bf16, accum fp32, hpre bf16.
// 4-edges-per-instruction (16-lane groups) + 32-edge window = 8 independent
// csr+gather chains in flight per wave. Tail branchless (clamp + zero weight).
__global__ __launch_bounds__(256) void k_agg(const unsigned short* __restrict__ hw,
                                             const int* __restrict__ offs,
                                             const unsigned int* __restrict__ csr,
                                             const float* __restrict__ dinv,
                                             const float* __restrict__ bias,
                                             unsigned short* __restrict__ hpre,
                                             float* __restrict__ stats) {
    __shared__ float sred[128];
    if (threadIdx.x < 128) sred[threadIdx.x] = 0.f;
    __syncthreads();
    int lane = threadIdx.x & 63;
    int fq = lane & 15;   // feature quad: features 4*fq .. 4*fq+3
    int eg = lane >> 4;   // edge group 0..3
    int wave = blockIdx.x * 4 + (threadIdx.x >> 6);
    int nw = AGG_GRID * 4;
    const ushort4* hw4 = (const ushort4*)hw;   // row v = hw4[v*16 + fq]
    float4 b4 = *(const float4*)&bias[fq * 4];
    float sx = 0.f, sy = 0.f, sz = 0.f, sw = 0.f;      // lsum per feature quad
    float qx = 0.f, qy = 0.f, qz = 0.f, qw = 0.f;      // lsq per feature quad
    for (int v = wave; v < N_NODES; v += nw) {
        float dv = dinv[v];
        int s = offs[v], e = offs[v + 1];
        float ax = 0.f, ay = 0.f, az = 0.f, aw = 0.f;
        for (int j = s; j < e; j += 32) {
            #pragma unroll
            for (int t = 0; t < 8; ++t) {
                int idx = j + 4 * t + eg;
                unsigned q = csr[min(idx, e - 1)];
                float w = __uint_as_float(q & 0xFFFF0000u);  // bf16 weight in high half
                w = (idx < e) ? w : 0.f;
                ushort4 h = hw4[(size_t)(q & 0xFFFFu) * 16 + fq];
                ax += w * bf2f(h.x);
                ay += w * bf2f(h.y);
                az += w * bf2f(h.z);
                aw += w * bf2f(h.w);
            }
        }
        // combine the 4 edge-groups (all lanes end with the full sum)
        #pragma unroll
        for (int m = 16; m < 64; m <<= 1) {
            ax += __shfl_xor(ax, m);
            ay += __shfl_xor(ay, m);
            az += __shfl_xor(az, m);
            aw += __shfl_xor(aw, m);
        }
        ushort4 hv = hw4[(size_t)v * 16 + fq];
        float dv2 = dv * dv;
        float rx = dv * ax + dv2 * bf2f(hv.x) + b4.x;
        float ry = dv * ay + dv2 * bf2f(hv.y) + b4.y;
        float rz = dv * az + dv2 * bf2f(hv.z) + b4.z;
        float rw = dv * aw + dv2 * bf2f(hv.w) + b4.w;
        if (lane < 16) {
            ushort4 o;
            o.x = f2bf(rx); o.y = f2bf(ry); o.z = f2bf(rz); o.w = f2bf(rw);
            *(ushort4*)&hpre[(size_t)v * 64 + fq * 4] = o;
        }
        sx += rx; sy += ry; sz += rz; sw += rw;
        qx += rx * rx; qy += ry * ry; qz += rz * rz; qw += rw * rw;
    }
    if (lane < 16) {  // groups 1-3 hold identical copies — count once
        atomicAdd(&sred[4 * fq + 0], sx);
        atomicAdd(&sred[4 * fq + 1], sy);
        atomicAdd(&sred[4 * fq + 2], sz);
        atomicAdd(&sred[4 * fq + 3], sw);
        atomicAdd(&sred[64 + 4 * fq + 0], qx);
        atomicAdd(&sred[64 + 4 * fq + 1], qy);
        atomicAdd(&sred[64 + 4 * fq + 2], qz);
        atomicAdd(&sred[64 + 4 * fq + 3], qw);
    }
    __syncthreads();
    if (threadIdx.x < 128) atomicAdd(&stats[threadIdx.x], sred[threadIdx.x]);
}

// one block per graph: norm+relu layer-3 rows (bf16 hpre), register max/sum,
// LDS tree-reduce, then fused head MLP. Zero atomics.
__global__ __launch_bounds__(256) void k_pool(const unsigned short* __restrict__ hpre,
                                              const float* __restrict__ stats,
                                              const float* __restrict__ gamma,
                                              const float* __restrict__ beta,
                                              const int* __restrict__ gstart,
                                              const float* __restrict__ lw1,
                                              const float* __restrict__ lb1,
                                              const float* __restrict__ lw2,
                                              const float* __restrict__ lb2,
                                              float* __restrict__ out) {
    __shared__ float smax[4][64];
    __shared__ float ssum[4][64];
    __shared__ float emb[192];
    __shared__ float hid[64];
    int g = blockIdx.x;
    int lane = threadIdx.x & 63;
    int wid = threadIdx.x >> 6;
    int s = gstart[g], e = gstart[g + 1];

    const float invN = 1.0f / (float)N_NODES;
    float mu = stats[lane] * invN;
    float var = stats[64 + lane] * invN - mu * mu;
    float sc = rsqrtf(var + EPSF) * gamma[lane];
    float sh = beta[lane] - mu * sc;

    float mx = 0.f, sm = 0.f;  // post-relu values are >= 0; empty graph -> 0 (matches ref)
    for (int v = s + wid; v < e; v += 4) {
        float h = fmaxf(bf2f(hpre[(size_t)v * 64 + lane]) * sc + sh, 0.f);
        mx = fmaxf(mx, h);
        sm += h;
    }
    smax[wid][lane] = mx;
    ssum[wid][lane] = sm;
    __syncthreads();
    if (wid == 0) {
        float m = fmaxf(fmaxf(smax[0][lane], smax[1][lane]), fmaxf(smax[2][lane], smax[3][lane]));
        float su = ssum[0][lane] + ssum[1][lane] + ssum[2][lane] + ssum[3][lane];
        float inv = 1.0f / fmaxf((float)(e - s), 1.0f);
        emb[lane] = m;
        emb[64 + lane] = su * inv;
        emb[128 + lane] = su;
    }
    __syncthreads();
    if (wid == 0) {
        float acc = lb1[lane];
        #pragma unroll 4
        for (int k = 0; k < 192; ++k) acc += emb[k] * lw1[k * 64 + lane];
        hid[lane] = fmaxf(acc, 0.f);
    }
    __syncthreads();
    if (threadIdx.x < N_CLASSES) {
        int j = threadIdx.x;
        float o = lb2[j];
        #pragma unroll 8
        for (int k = 0; k < 64; ++k) o += hid[k] * lw2[k * 10 + j];
        out[(size_t)g * 10 + j] = o;
    }
}

// ---------------- launch ----------------

extern "C" void kernel_launch(void* const* d_in, const int* in_sizes, int n_in,
                              void* d_out, int out_size, void* d_ws, size_t ws_size,
                              hipStream_t stream) {
    const float* x     = (const float*)d_in[0];
    const int* eidx    = (const int*)d_in[1];
    const int* batch   = (const int*)d_in[2];
    const float* W1    = (const float*)d_in[3];
    const float* b1    = (const float*)d_in[4];
    const float* W2    = (const float*)d_in[5];
    const float* b2    = (const float*)d_in[6];
    const float* gamma = (const float*)d_in[7];
    const float* beta  = (const float*)d_in[8];
    const float* lw1   = (const float*)d_in[9];
    const float* lb1   = (const float*)d_in[10];
    const float* lw2   = (const float*)d_in[11];
    const float* lb2   = (const float*)d_in[12];
    float* out = (float*)d_out;

    const int* e_src = eidx;
    const int* e_dst = eidx + N_EDGES;

    char* p = (char*)d_ws;
    auto carve = [&](size_t bytes) { char* r = p; p += (bytes + 255) & ~(size_t)255; return r; };
    // zero-initialized region (one memset covers these)
    int*   cnt   = (int*)carve((size_t)N_NODES * 4);
    float* stats = (float*)carve(3 * 128 * 4);
    size_t zero_bytes = (size_t)(p - (char*)d_ws);
    // scratch (no init needed)
    int*   offs   = (int*)carve((size_t)(N_NODES + 1) * 4);
    int*   bcur   = (int*)carve((size_t)NB * 4);
    float* dinv   = (float*)carve((size_t)N_NODES * 4);
    int*   gstart = (int*)carve((size_t)(N_GRAPHS + 1) * 4);
    uint2* binned = (uint2*)carve((size_t)N_EDGES * 8);
    unsigned int* csr = (unsigned int*)carve((size_t)N_EDGES * 4);
    unsigned short* B0 = (unsigned short*)carve((size_t)N_NODES * 64 * 2);  // bf16 h@W (gather src)
    unsigned short* B1 = (unsigned short*)carve((size_t)N_NODES * 64 * 2);  // bf16 h_pre

    hipMemsetAsync(d_ws, 0, zero_bytes, stream);

    // degree hist -> scan -> bucket multisplit -> bucket-local csr scatter
    k_hist<<<(N_EDGES + 255) / 256, 256, 0, stream>>>(e_dst, cnt);
    k_scan<<<1, 1024, 0, stream>>>(cnt, offs, bcur, dinv);
    k_bin<<<(N_EDGES + BIN_CHUNK - 1) / BIN_CHUNK, 256, 0, stream>>>(e_src, e_dst, dinv, bcur, binned);
    k_fill2<<<NB, 256, 0, stream>>>(binned, offs, csr);
    k_bounds<<<(N_NODES + 255) / 256, 256, 0, stream>>>(batch, gstart);

    const int GEMM_GRID = (N_NODES + 63) / 64;  // 782
    // layer 1
    k_gemm<128, false><<<GEMM_GRID, 256, 0, stream>>>(x, W1, B0, nullptr, nullptr, nullptr);
    k_agg<<<AGG_GRID, 256, 0, stream>>>(B0, offs, csr, dinv, b1, B1, stats);
    // layer 2 (norm+relu of layer 1 fused into A-stage, bf16 A)
    k_gemm<64, true><<<GEMM_GRID, 256, 0, stream>>>(B1, W2, B0, stats, gamma, beta);
    k_agg<<<AGG_GRID, 256, 0, stream>>>(B0, offs, csr, dinv, b2, B1, stats + 128);
    // layer 3 (norm+relu of layer 2 fused into A-stage, bf16 A)
    k_gemm<64, true><<<GEMM_GRID, 256, 0, stream>>>(B1, W2, B0, stats + 128, gamma, beta);
    k_agg<<<AGG_GRID, 256, 0, stream>>>(B0, offs, csr, dinv, b2, B1, stats + 256);
    // norm+relu layer 3 + segmented pooling + head MLP (no atomics)
    k_pool<<<N_GRAPHS, 256, 0, stream>>>(B1, stats + 256, gamma, beta, gstart,
                                         lw1, lb1, lw2, lb2, out);
}